// Round 1
// baseline (1624.426 us; speedup 1.0000x reference)
//
#include <hip/hip_runtime.h>

// ODENet: y_{t+1} = y_t + f(x_t, y_t),  f = W3ᵀ tanh(W2ᵀ tanh(x*W1[0] + y*W1[1] + b1) + b2) + b3
// out[t][b] = y_t (pre-update state).  SEQ=2048 sequential steps, BATCH=512 independent chains.
//
// Mapping: 256 WGs x 512 threads (8 waves). WG g owns chains {2g, 2g+1}.
// Main matvec (K=256) via mfma_f32_16x16x32_bf16 with M padded 2->16.
// W2 held in VGPRs as pre-packed bf16 B-fragments (prep kernel -> d_ws).
// 2 barriers per step; h1 staged through a 1KB LDS buffer.

#define SEQ 2048
#define BATCH 512
#define HID 256

typedef __bf16 bf16x8 __attribute__((ext_vector_type(8)));
typedef short short8 __attribute__((ext_vector_type(8)));
typedef float f32x4 __attribute__((ext_vector_type(4)));

__device__ __forceinline__ unsigned short f2bf_rne(float f) {
  unsigned u = __builtin_bit_cast(unsigned, f);
  u += 0x7fffu + ((u >> 16) & 1u);
  return (unsigned short)(u >> 16);
}

__device__ __forceinline__ float tanh_fast(float x) {
  float cx = fminf(fmaxf(x, -10.f), 10.f);
  float t = __builtin_amdgcn_exp2f(cx * 2.8853900817779268f); // exp(2x)
  return (t - 1.f) * __builtin_amdgcn_rcpf(t + 1.f);
}

// Pack W2 (256x256 fp32, row-major [k][c]) into bf16 B-fragments.
// Element order: ws[(((tile*8)+kc)*64 + lane)*8 + e] = bf16(W2[k][c])
//   k = kc*32 + (lane>>4)*8 + e   (our chosen lane->k bijection, used for A too)
//   c = tile*16 + (lane&15)
__global__ void pack_w2_kernel(const float* __restrict__ W2,
                               unsigned short* __restrict__ ws) {
  int idx = blockIdx.x * 256 + threadIdx.x;     // 0..65535
  int e    = idx & 7;
  int l    = (idx >> 3) & 63;
  int kc   = (idx >> 9) & 7;
  int tile = idx >> 12;                         // 0..15
  int k = kc * 32 + (l >> 4) * 8 + e;
  int c = tile * 16 + (l & 15);
  ws[idx] = f2bf_rne(W2[k * HID + c]);
}

__global__ __launch_bounds__(512, 2) void odenet_kernel(
    const float* __restrict__ x, const float* __restrict__ W1,
    const float* __restrict__ b1, const unsigned short* __restrict__ wsW2,
    const float* __restrict__ b2, const float* __restrict__ W3,
    const float* __restrict__ b3, const float* __restrict__ state0,
    float* __restrict__ out) {
  __shared__ __align__(16) unsigned short A_lds[2 * HID]; // h1 as bf16, rows 0..1
  __shared__ __align__(16) float partial[2][8];           // [row][wave]

  const int tid  = threadIdx.x;
  const int lane = tid & 63;
  const int wave = tid >> 6;   // 0..7
  const int rh   = tid >> 8;   // 0/1: this thread's h1-row duty
  const int j    = tid & 255;  // this thread's h1-column duty
  const int b0   = blockIdx.x * 2;

  // --- persistent constants ---
  const float w10 = W1[j];
  const float w11 = W1[HID + j];
  const float b1j = b1[j];
  const float b3v = b3[0];
  const int   c0   = wave * 32 + (lane & 15);
  const int   c1   = c0 + 16;
  const float b2c0 = b2[c0], b2c1 = b2[c1];
  const float w3c0 = W3[c0], w3c1 = W3[c1];

  // --- B fragments: this wave owns columns [wave*32, wave*32+32) ---
  short8 bf0[8], bf1[8];
  {
    const short8* wp = (const short8*)wsW2;
    const int t0 = wave * 2, t1 = t0 + 1;
#pragma unroll
    for (int kc = 0; kc < 8; ++kc) {
      bf0[kc] = wp[(t0 * 8 + kc) * 64 + lane];
      bf1[kc] = wp[(t1 * 8 + kc) * 64 + lane];
    }
  }

  // --- A fragments: only lanes with (lane&15)<2 hold real rows; rest stay 0 ---
  const short8 zero8 = {0, 0, 0, 0, 0, 0, 0, 0};
  short8 areg[8];
#pragma unroll
  for (int kc = 0; kc < 8; ++kc) areg[kc] = zero8;
  const bool aread = ((lane & 15) < 2);
  const int  aoff  = (lane & 15) * HID + (lane >> 4) * 8; // ushort index

  float y = state0[b0 + rh];

  const float* xp = x + b0 + rh;
  float* yo = out + b0 + rh;

  // x prefetch double buffer (8 steps ahead)
  float xb[8], xn[8];
#pragma unroll
  for (int i = 0; i < 8; ++i) xb[i] = xp[i * BATCH];

  for (int tb = 0; tb < SEQ; tb += 8) {
    // issue next block's x loads early (latency hidden under 8 steps)
#pragma unroll
    for (int i = 0; i < 8; ++i) {
      int tn = tb + 8 + i;
      tn = tn > (SEQ - 1) ? (SEQ - 1) : tn;
      xn[i] = xp[tn * BATCH];
    }

#pragma unroll
    for (int i = 0; i < 8; ++i) {
      const int t = tb + i;

      // h1[rh][j] = tanh(x*W1[0,j] + y*W1[1,j] + b1[j]) -> LDS (bf16)
      const float pre = xb[i] * w10 + (y * w11 + b1j);
      A_lds[rh * HID + j] = f2bf_rne(tanh_fast(pre));
      __syncthreads(); // bar1: h1 visible

      // A-fragments (exec-masked: 8 real lanes; pad lanes keep zeros)
      if (aread) {
#pragma unroll
        for (int kc = 0; kc < 8; ++kc)
          areg[kc] = *(const short8*)&A_lds[aoff + kc * 32];
      }

      // h2 pre-activation: two 16-col tiles per wave, K=256 over 8 chunks
      f32x4 acc0 = {0.f, 0.f, 0.f, 0.f};
      f32x4 acc1 = {0.f, 0.f, 0.f, 0.f};
#pragma unroll
      for (int kc = 0; kc < 8; ++kc) {
        const bf16x8 a = __builtin_bit_cast(bf16x8, areg[kc]);
        acc0 = __builtin_amdgcn_mfma_f32_16x16x32_bf16(
            a, __builtin_bit_cast(bf16x8, bf0[kc]), acc0, 0, 0, 0);
        acc1 = __builtin_amdgcn_mfma_f32_16x16x32_bf16(
            a, __builtin_bit_cast(bf16x8, bf1[kc]), acc1, 0, 0, 0);
      }

      // h2 = tanh(acc + b2); partial out = h2 . W3 (rows 0,1 live in lanes 0..15, regs 0,1)
      float p0 = 0.f, p1 = 0.f;
      if (lane < 16) {
        p0 = tanh_fast(acc0[0] + b2c0) * w3c0 + tanh_fast(acc1[0] + b2c1) * w3c1;
        p1 = tanh_fast(acc0[1] + b2c0) * w3c0 + tanh_fast(acc1[1] + b2c1) * w3c1;
      }
      // reduce over the 16-lane column group
#pragma unroll
      for (int m = 1; m <= 8; m <<= 1) {
        p0 += __shfl_xor(p0, m, 64);
        p1 += __shfl_xor(p1, m, 64);
      }
      if (lane == 0) {
        partial[0][wave] = p0;
        partial[1][wave] = p1;
      }
      __syncthreads(); // bar2: partials visible

      // every thread folds the 8 wave-partials for its row -> identical y update
      const f32x4 q0 = *(const f32x4*)&partial[rh][0];
      const f32x4 q1 = *(const f32x4*)&partial[rh][4];
      const float f = ((q0[0] + q0[1]) + (q0[2] + q0[3])) +
                      ((q1[0] + q1[1]) + (q1[2] + q1[3])) + b3v;
      const float y_old = y;
      y += f; // DT = 1.0
      if (j == 0) yo[t * BATCH] = y_old; // ys[t] = pre-update state
    }

#pragma unroll
    for (int i = 0; i < 8; ++i) xb[i] = xn[i];
  }
}

extern "C" void kernel_launch(void* const* d_in, const int* in_sizes, int n_in,
                              void* d_out, int out_size, void* d_ws, size_t ws_size,
                              hipStream_t stream) {
  const float* x  = (const float*)d_in[0];
  const float* W1 = (const float*)d_in[1];
  const float* b1 = (const float*)d_in[2];
  const float* W2 = (const float*)d_in[3];
  const float* b2 = (const float*)d_in[4];
  const float* W3 = (const float*)d_in[5];
  const float* b3 = (const float*)d_in[6];
  const float* s0 = (const float*)d_in[7];
  unsigned short* ws = (unsigned short*)d_ws; // 65536 bf16 = 128 KB
  float* out = (float*)d_out;

  pack_w2_kernel<<<256, 256, 0, stream>>>(W2, ws);
  odenet_kernel<<<256, 512, 0, stream>>>(x, W1, b1, ws, b2, W3, b3, s0, out);
}

// Round 2
// 1462.885 us; speedup vs baseline: 1.1104x; 1.1104x over previous
//
#include <hip/hip_runtime.h>

// ODENet: y_{t+1} = y_t + f(x_t, y_t),  f = W3^T tanh(W2^T tanh(x*W1[0] + y*W1[1] + b1) + b2) + b3
// out[t][b] = y_t (pre-update state).  SEQ=2048 sequential steps, BATCH=512 independent chains.
//
// Mapping: 256 WGs x 512 threads (8 waves). WG g owns chains {2g, 2g+1}.
// Main matvec (K=256) via mfma_f32_16x16x32_bf16 with M padded 2->16 (4 accumulator chains).
// W2 held in VGPRs as pre-packed bf16 B-fragments (prep kernel -> d_ws).
// Reduction over 16 lanes via DPP row_shr adds (no ds_swizzle). Padé tanh (1 trans op).

#define SEQ 2048
#define BATCH 512
#define HID 256

typedef __bf16 bf16x8 __attribute__((ext_vector_type(8)));
typedef short short8 __attribute__((ext_vector_type(8)));
typedef float f32x4 __attribute__((ext_vector_type(4)));

__device__ __forceinline__ unsigned short f2bf_rne(float f) {
  unsigned u = __builtin_bit_cast(unsigned, f);
  u += 0x7fffu + ((u >> 16) & 1u);
  return (unsigned short)(u >> 16);
}

// Padé [7/6] tanh, clamp +-4.5; max abs err ~6.5e-4 (at/beyond clamp), <1e-5 for |x|<2.5.
__device__ __forceinline__ float tanh_pade(float x) {
  float cx = __builtin_amdgcn_fmed3f(x, -4.5f, 4.5f);
  float u = cx * cx;
  float num = cx * (10395.f + u * (1260.f + 21.f * u));
  float den = 10395.f + u * (4725.f + u * (210.f + u));
  return num * __builtin_amdgcn_rcpf(den);
}

// Sum over each 16-lane DPP row; result valid in lane 15 of the row (zeros elsewhere shifted in).
__device__ __forceinline__ float row16_sum_to_lane15(float v) {
  int s;
  s = __builtin_amdgcn_update_dpp(0, __builtin_bit_cast(int, v), 0x111, 0xf, 0xf, true); // row_shr:1
  v += __builtin_bit_cast(float, s);
  s = __builtin_amdgcn_update_dpp(0, __builtin_bit_cast(int, v), 0x112, 0xf, 0xf, true); // row_shr:2
  v += __builtin_bit_cast(float, s);
  s = __builtin_amdgcn_update_dpp(0, __builtin_bit_cast(int, v), 0x114, 0xf, 0xf, true); // row_shr:4
  v += __builtin_bit_cast(float, s);
  s = __builtin_amdgcn_update_dpp(0, __builtin_bit_cast(int, v), 0x118, 0xf, 0xf, true); // row_shr:8
  v += __builtin_bit_cast(float, s);
  return v;
}

// Pack W2 (256x256 fp32, row-major [k][c]) into bf16 B-fragments.
// ws[(((tile*8)+kc)*64 + lane)*8 + e] = bf16(W2[k][c]) with
//   k = kc*32 + (lane>>4)*8 + e,  c = tile*16 + (lane&15)
__global__ void pack_w2_kernel(const float* __restrict__ W2,
                               unsigned short* __restrict__ ws) {
  int idx = blockIdx.x * 256 + threadIdx.x;     // 0..65535
  int e    = idx & 7;
  int l    = (idx >> 3) & 63;
  int kc   = (idx >> 9) & 7;
  int tile = idx >> 12;                         // 0..15
  int k = kc * 32 + (l >> 4) * 8 + e;
  int c = tile * 16 + (l & 15);
  ws[idx] = f2bf_rne(W2[k * HID + c]);
}

__global__ __launch_bounds__(512, 2) void odenet_kernel(
    const float* __restrict__ x, const float* __restrict__ W1,
    const float* __restrict__ b1, const unsigned short* __restrict__ wsW2,
    const float* __restrict__ b2, const float* __restrict__ W3,
    const float* __restrict__ b3, const float* __restrict__ state0,
    float* __restrict__ out) {
  __shared__ __align__(16) unsigned short A_lds[2 * HID]; // h1 as bf16, rows 0..1
  __shared__ __align__(16) float partial[2][8];           // [row][wave]

  const int tid  = threadIdx.x;
  const int lane = tid & 63;
  const int wave = tid >> 6;   // 0..7
  const int rh   = tid >> 8;   // 0/1: this thread's h1-row duty
  const int j    = tid & 255;  // this thread's h1-column duty
  const int b0   = blockIdx.x * 2;

  // --- persistent constants ---
  const float w10 = W1[j];
  const float w11 = W1[HID + j];
  const float b1j = b1[j];
  const float b3v = b3[0];
  const int   c0   = wave * 32 + (lane & 15);
  const int   c1   = c0 + 16;
  const float b2c0 = b2[c0], b2c1 = b2[c1];
  const float w3c0 = W3[c0], w3c1 = W3[c1];

  // --- B fragments: this wave owns columns [wave*32, wave*32+32) ---
  short8 bf0[8], bf1[8];
  {
    const short8* wp = (const short8*)wsW2;
    const int t0 = wave * 2, t1 = t0 + 1;
#pragma unroll
    for (int kc = 0; kc < 8; ++kc) {
      bf0[kc] = wp[(t0 * 8 + kc) * 64 + lane];
      bf1[kc] = wp[(t1 * 8 + kc) * 64 + lane];
    }
  }

  // --- A fragments: only lanes with (lane&15)<2 hold real rows; rest stay 0 ---
  const short8 zero8 = {0, 0, 0, 0, 0, 0, 0, 0};
  short8 areg[8];
#pragma unroll
  for (int kc = 0; kc < 8; ++kc) areg[kc] = zero8;
  const bool aread = ((lane & 15) < 2);
  const int  aoff  = (lane & 15) * HID + (lane >> 4) * 8; // ushort index

  float y = state0[b0 + rh];

  const float* xp = x + b0 + rh;
  float* yo = out + b0 + rh;

  // x prefetch double buffer (8 steps ahead); xa = x*W1[0,j] + b1[j] precomputed
  float xb[8], xn[8], xa[8];
#pragma unroll
  for (int i = 0; i < 8; ++i) xb[i] = xp[i * BATCH];
#pragma unroll
  for (int i = 0; i < 8; ++i) xa[i] = xb[i] * w10 + b1j;

  for (int tb = 0; tb < SEQ; tb += 8) {
    // issue next block's x loads early (no clamp: guarded block granularity)
    if (tb + 8 < SEQ) {
      const float* xq = xp + (tb + 8) * BATCH;
#pragma unroll
      for (int i = 0; i < 8; ++i) xn[i] = xq[i * BATCH];
    }

#pragma unroll
    for (int i = 0; i < 8; ++i) {
      const int t = tb + i;

      // h1[rh][j] = tanh(x*W1[0,j] + y*W1[1,j] + b1[j]) -> LDS (bf16)
      const float pre = __builtin_fmaf(y, w11, xa[i]);
      A_lds[tid & 511] = f2bf_rne(tanh_pade(pre));
      __syncthreads(); // bar1: h1 visible

      // A-fragments (exec-masked: 8 real lanes; pad lanes keep zeros)
      if (aread) {
#pragma unroll
        for (int kc = 0; kc < 8; ++kc)
          areg[kc] = *(const short8*)&A_lds[aoff + kc * 32];
      }

      // h2 pre-activation: two 16-col tiles per wave, K=256 over 8 chunks,
      // 4 accumulator chains (dep distance 4) then pairwise combine.
      f32x4 a00 = {0.f, 0.f, 0.f, 0.f};
      f32x4 a10 = {0.f, 0.f, 0.f, 0.f};
      f32x4 a01 = {0.f, 0.f, 0.f, 0.f};
      f32x4 a11 = {0.f, 0.f, 0.f, 0.f};
#pragma unroll
      for (int kc = 0; kc < 4; ++kc) {
        const bf16x8 aL = __builtin_bit_cast(bf16x8, areg[kc]);
        const bf16x8 aH = __builtin_bit_cast(bf16x8, areg[kc + 4]);
        a00 = __builtin_amdgcn_mfma_f32_16x16x32_bf16(
            aL, __builtin_bit_cast(bf16x8, bf0[kc]), a00, 0, 0, 0);
        a10 = __builtin_amdgcn_mfma_f32_16x16x32_bf16(
            aL, __builtin_bit_cast(bf16x8, bf1[kc]), a10, 0, 0, 0);
        a01 = __builtin_amdgcn_mfma_f32_16x16x32_bf16(
            aH, __builtin_bit_cast(bf16x8, bf0[kc + 4]), a01, 0, 0, 0);
        a11 = __builtin_amdgcn_mfma_f32_16x16x32_bf16(
            aH, __builtin_bit_cast(bf16x8, bf1[kc + 4]), a11, 0, 0, 0);
      }
      const f32x4 acc0 = a00 + a01;
      const f32x4 acc1 = a10 + a11;

      // h2 = tanh(acc + b2); partial = h2 . W3 (rows 0,1 live in lanes 0..15, regs 0,1)
      float p0 = 0.f, p1 = 0.f;
      if (lane < 16) {
        p0 = tanh_pade(acc0[0] + b2c0) * w3c0 + tanh_pade(acc1[0] + b2c1) * w3c1;
        p1 = tanh_pade(acc0[1] + b2c0) * w3c0 + tanh_pade(acc1[1] + b2c1) * w3c1;
      }
      // reduce over the 16-lane column group via DPP (no LDS/swizzle)
      p0 = row16_sum_to_lane15(p0);
      p1 = row16_sum_to_lane15(p1);
      if (lane == 15) {
        partial[0][wave] = p0;
        partial[1][wave] = p1;
      }
      __syncthreads(); // bar2: partials visible

      // every thread folds the 8 wave-partials for its row -> identical y update
      const f32x4 q0 = *(const f32x4*)&partial[rh][0];
      const f32x4 q1 = *(const f32x4*)&partial[rh][4];
      const float f = ((q0[0] + q0[1]) + (q0[2] + q0[3])) +
                      ((q1[0] + q1[1]) + (q1[2] + q1[3])) + b3v;
      const float y_old = y;
      y += f; // DT = 1.0
      if (j == 0) yo[t * BATCH] = y_old; // ys[t] = pre-update state
    }

    if (tb + 8 < SEQ) {
#pragma unroll
      for (int i = 0; i < 8; ++i) xb[i] = xn[i];
#pragma unroll
      for (int i = 0; i < 8; ++i) xa[i] = xb[i] * w10 + b1j;
    }
  }
}

extern "C" void kernel_launch(void* const* d_in, const int* in_sizes, int n_in,
                              void* d_out, int out_size, void* d_ws, size_t ws_size,
                              hipStream_t stream) {
  const float* x  = (const float*)d_in[0];
  const float* W1 = (const float*)d_in[1];
  const float* b1 = (const float*)d_in[2];
  const float* W2 = (const float*)d_in[3];
  const float* b2 = (const float*)d_in[4];
  const float* W3 = (const float*)d_in[5];
  const float* b3 = (const float*)d_in[6];
  const float* s0 = (const float*)d_in[7];
  unsigned short* ws = (unsigned short*)d_ws; // 65536 bf16 = 128 KB
  float* out = (float*)d_out;

  pack_w2_kernel<<<256, 256, 0, stream>>>(W2, ws);
  odenet_kernel<<<256, 512, 0, stream>>>(x, W1, b1, ws, b2, W3, b3, s0, out);
}

// Round 3
// 1445.403 us; speedup vs baseline: 1.1239x; 1.0121x over previous
//
#include <hip/hip_runtime.h>

// ODENet: y_{t+1} = y_t + f(x_t, y_t),  f = W3^T tanh(W2^T tanh(x*W1[0] + y*W1[1] + b1) + b2) + b3
// out[t][b] = y_t (pre-update state).  SEQ=2048 sequential steps, BATCH=512 independent chains.
//
// Round-3 mapping: 256 WGs x 256 threads (4 waves = 1 wave/SIMD, zero issue contention).
// WG g owns chains {2g, 2g+1}, placed at MFMA rows m=0 and m=4 so the C-layout
// (row=(lane>>4)*4+reg) puts chain0 in lanes 0-15/reg0 and chain1 in lanes 16-31/reg0.
// Each wave owns 64 columns (4 tiles x 8 k-chunks = 32 MFMAs/step).
// W2 held in VGPRs/AGPRs as pre-packed bf16 B-fragments (prep kernel -> d_ws).

#define SEQ 2048
#define BATCH 512
#define HID 256

typedef __bf16 bf16x8 __attribute__((ext_vector_type(8)));
typedef short short8 __attribute__((ext_vector_type(8)));
typedef float f32x4 __attribute__((ext_vector_type(4)));

__device__ __forceinline__ unsigned short f2bf_rne(float f) {
  unsigned u = __builtin_bit_cast(unsigned, f);
  u += 0x7fffu + ((u >> 16) & 1u);
  return (unsigned short)(u >> 16);
}

// Padé [7/6] tanh, clamp +-4.5; max abs err ~6.5e-4 (at/beyond clamp), <1e-5 for |x|<2.5.
__device__ __forceinline__ float tanh_pade(float x) {
  float cx = __builtin_amdgcn_fmed3f(x, -4.5f, 4.5f);
  float u = cx * cx;
  float num = cx * (10395.f + u * (1260.f + 21.f * u));
  float den = 10395.f + u * (4725.f + u * (210.f + u));
  return num * __builtin_amdgcn_rcpf(den);
}

// Sum over each 16-lane DPP row; result valid in lane 15 of the row (zeros shifted in).
__device__ __forceinline__ float row16_sum_to_lane15(float v) {
  int s;
  s = __builtin_amdgcn_update_dpp(0, __builtin_bit_cast(int, v), 0x111, 0xf, 0xf, true);
  v += __builtin_bit_cast(float, s);
  s = __builtin_amdgcn_update_dpp(0, __builtin_bit_cast(int, v), 0x112, 0xf, 0xf, true);
  v += __builtin_bit_cast(float, s);
  s = __builtin_amdgcn_update_dpp(0, __builtin_bit_cast(int, v), 0x114, 0xf, 0xf, true);
  v += __builtin_bit_cast(float, s);
  s = __builtin_amdgcn_update_dpp(0, __builtin_bit_cast(int, v), 0x118, 0xf, 0xf, true);
  v += __builtin_bit_cast(float, s);
  return v;
}

// Pack W2 (256x256 fp32, row-major [k][c]) into bf16 B-fragments.
// ws[(((tile*8)+kc)*64 + lane)*8 + e] = bf16(W2[k][c]) with
//   k = kc*32 + (lane>>4)*8 + e,  c = tile*16 + (lane&15)
__global__ void pack_w2_kernel(const float* __restrict__ W2,
                               unsigned short* __restrict__ ws) {
  int idx = blockIdx.x * 256 + threadIdx.x;     // 0..65535
  int e    = idx & 7;
  int l    = (idx >> 3) & 63;
  int kc   = (idx >> 9) & 7;
  int tile = idx >> 12;                         // 0..15
  int k = kc * 32 + (l >> 4) * 8 + e;
  int c = tile * 16 + (l & 15);
  ws[idx] = f2bf_rne(W2[k * HID + c]);
}

__global__ __launch_bounds__(256, 1) void odenet_kernel(
    const float* __restrict__ x, const float* __restrict__ W1,
    const float* __restrict__ b1, const unsigned short* __restrict__ wsW2,
    const float* __restrict__ b2, const float* __restrict__ W3,
    const float* __restrict__ b3, const float* __restrict__ state0,
    float* __restrict__ out) {
  __shared__ __align__(16) unsigned short A_lds[2 * HID]; // h1 bf16, rows 0..1
  __shared__ __align__(16) float partial[2][4];           // [chain][wave]

  const int tid  = threadIdx.x;   // 0..255 == column j
  const int lane = tid & 63;
  const int wave = tid >> 6;      // 0..3
  const int j    = tid;
  const int b0   = blockIdx.x * 2;

  // --- persistent constants ---
  const float w10 = W1[j];
  const float w11 = W1[HID + j];
  const float b1j = b1[j];
  const float b3v = b3[0];
  float b2c[4], w3c[4];
#pragma unroll
  for (int t = 0; t < 4; ++t) {
    const int c = wave * 64 + t * 16 + (lane & 15);
    b2c[t] = b2[c];
    w3c[t] = W3[c];
  }

  // --- B fragments: wave owns tiles wave*4 .. wave*4+3 (64 columns) ---
  short8 bf[4][8];
  {
    const short8* wp = (const short8*)wsW2;
#pragma unroll
    for (int t = 0; t < 4; ++t)
#pragma unroll
      for (int kc = 0; kc < 8; ++kc)
        bf[t][kc] = wp[((wave * 4 + t) * 8 + kc) * 64 + lane];
  }

  // --- A fragments: rows m=0 (lane&15==0) and m=4 (lane&15==4) are real ---
  const short8 zero8 = {0, 0, 0, 0, 0, 0, 0, 0};
  short8 areg[8];
#pragma unroll
  for (int kc = 0; kc < 8; ++kc) areg[kc] = zero8;
  const bool aread = ((lane & 11) == 0);           // lane&15 in {0,4}
  const int  arow  = (lane >> 2) & 1;              // 0 -> chain0, 1 -> chain1
  const int  aoff  = arow * HID + (lane >> 4) * 8; // ushort index

  float y0 = state0[b0];
  float y1 = state0[b0 + 1];

  const float* xp = x + b0;
  float* yo = out + b0;

  // x prefetch double buffer (8 steps ahead); xa_r = x_r*W1[0,j] + b1[j]
  float2 xb[8], xn[8];
  float xa0[8], xa1[8];
#pragma unroll
  for (int i = 0; i < 8; ++i) xb[i] = *(const float2*)&xp[i * BATCH];
#pragma unroll
  for (int i = 0; i < 8; ++i) {
    xa0[i] = xb[i].x * w10 + b1j;
    xa1[i] = xb[i].y * w10 + b1j;
  }

  for (int tb = 0; tb < SEQ; tb += 8) {
    if (tb + 8 < SEQ) {
      const float* xq = xp + (tb + 8) * BATCH;
#pragma unroll
      for (int i = 0; i < 8; ++i) xn[i] = *(const float2*)&xq[i * BATCH];
    }

#pragma unroll
    for (int i = 0; i < 8; ++i) {
      const int t = tb + i;

      // h1[r][j] = tanh(x_r*W1[0,j] + y_r*W1[1,j] + b1[j]) -> LDS (bf16)
      const float pre0 = __builtin_fmaf(y0, w11, xa0[i]);
      const float pre1 = __builtin_fmaf(y1, w11, xa1[i]);
      A_lds[j]       = f2bf_rne(tanh_pade(pre0));
      A_lds[HID + j] = f2bf_rne(tanh_pade(pre1));
      __syncthreads(); // bar1: h1 visible

      // A-fragments (8 active lanes; pad lanes keep zeros)
      if (aread) {
#pragma unroll
        for (int kc = 0; kc < 8; ++kc)
          areg[kc] = *(const short8*)&A_lds[aoff + kc * 32];
      }

      // h2 pre-activation: 4 column-tiles, K=256 over 8 chunks, 4 indep chains
      f32x4 acc[4];
#pragma unroll
      for (int t4 = 0; t4 < 4; ++t4) acc[t4] = f32x4{0.f, 0.f, 0.f, 0.f};
#pragma unroll
      for (int kc = 0; kc < 8; ++kc) {
        const bf16x8 a = __builtin_bit_cast(bf16x8, areg[kc]);
#pragma unroll
        for (int t4 = 0; t4 < 4; ++t4)
          acc[t4] = __builtin_amdgcn_mfma_f32_16x16x32_bf16(
              a, __builtin_bit_cast(bf16x8, bf[t4][kc]), acc[t4], 0, 0, 0);
      }

      // chain0 in lanes 0-15 reg0, chain1 in lanes 16-31 reg0.
      float s = 0.f;
      if (lane < 32) {
#pragma unroll
        for (int t4 = 0; t4 < 4; ++t4)
          s += tanh_pade(acc[t4][0] + b2c[t4]) * w3c[t4];
      }
      s = row16_sum_to_lane15(s);
      if ((lane & 15) == 15 && lane < 32)
        partial[lane >> 4][wave] = s;
      __syncthreads(); // bar2: partials visible

      const f32x4 q0 = *(const f32x4*)&partial[0][0];
      const f32x4 q1 = *(const f32x4*)&partial[1][0];
      const float f0 = ((q0[0] + q0[1]) + (q0[2] + q0[3])) + b3v;
      const float f1 = ((q1[0] + q1[1]) + (q1[2] + q1[3])) + b3v;
      const float y0o = y0, y1o = y1;
      y0 += f0; // DT = 1.0
      y1 += f1;
      if (tid == 0) {
        float2 o{y0o, y1o};
        *(float2*)&yo[t * BATCH] = o; // ys[t] = pre-update state
      }
    }

    if (tb + 8 < SEQ) {
#pragma unroll
      for (int i = 0; i < 8; ++i) xb[i] = xn[i];
#pragma unroll
      for (int i = 0; i < 8; ++i) {
        xa0[i] = xb[i].x * w10 + b1j;
        xa1[i] = xb[i].y * w10 + b1j;
      }
    }
  }
}

extern "C" void kernel_launch(void* const* d_in, const int* in_sizes, int n_in,
                              void* d_out, int out_size, void* d_ws, size_t ws_size,
                              hipStream_t stream) {
  const float* x  = (const float*)d_in[0];
  const float* W1 = (const float*)d_in[1];
  const float* b1 = (const float*)d_in[2];
  const float* W2 = (const float*)d_in[3];
  const float* b2 = (const float*)d_in[4];
  const float* W3 = (const float*)d_in[5];
  const float* b3 = (const float*)d_in[6];
  const float* s0 = (const float*)d_in[7];
  unsigned short* ws = (unsigned short*)d_ws; // 65536 bf16 = 128 KB
  float* out = (float*)d_out;

  pack_w2_kernel<<<256, 256, 0, stream>>>(W2, ws);
  odenet_kernel<<<256, 256, 0, stream>>>(x, W1, b1, ws, b2, W3, b3, s0, out);
}